// Round 14
// baseline (229.017 us; speedup 1.0000x reference)
//
#include <hip/hip_runtime.h>
#include <hip/hip_fp16.h>
#include <math.h>

#define Bn 16
#define Tn 2048
#define Fn 1025
#define KP 1056       // padded K = 33 * 32 (basisT row stride)
#define KROW 1064     // LDS u row stride in fp16
#define ROWS 16       // rows per block; 8 waves -> 2 rows/wave, wave-independent
#define Dn 64
#define EPSF 1e-6f

typedef __attribute__((ext_vector_type(8))) _Float16 f16x8;
typedef __attribute__((ext_vector_type(4))) _Float16 f16x4;
typedef __attribute__((ext_vector_type(4))) float f32x4;

__device__ inline float waveReduceSum(float v) {
#pragma unroll
  for (int off = 32; off > 0; off >>= 1) v += __shfl_xor(v, off, 64);
  return v;
}

// ---------------- prep: basisT[d][k] fp16 (normalized), spacing outputs ----------------
__global__ __launch_bounds__(256) void prep_kernel(
    const float* __restrict__ freq, const float* __restrict__ spacing,
    _Float16* __restrict__ basisT, float* __restrict__ out2, float* __restrict__ out3) {
  __shared__ float wsum[4];
  const int d = blockIdx.x;
  const int tid = threadIdx.x;
  const float sp = fmaxf(spacing[d], 1e-6f);

  float pv[5];
  float lsum = 0.f;
#pragma unroll
  for (int it = 0; it < 5; ++it) {
    int f = tid + 256 * it;
    float p = 0.f;
    if (f < Fn) {
      double arg = 6.2831853071795864769 * (double)(freq[f] / sp);
      p = 0.5f * (1.0f + (float)cos(arg));
      lsum += p;
    }
    pv[it] = p;
  }
  float s = waveReduceSum(lsum);
  if ((tid & 63) == 0) wsum[tid >> 6] = s;
  __syncthreads();
  float inv = 1.0f / fmaxf((wsum[0] + wsum[1] + wsum[2] + wsum[3]) * (1.0f / 1025.0f), EPSF);

#pragma unroll
  for (int it = 0; it < 5; ++it) {
    int f = tid + 256 * it;
    if (f < KP) basisT[(size_t)d * KP + f] = (_Float16)(pv[it] * inv);
  }
  if (tid == 0) {
    out2[d] = spacing[d];
    out3[d] = 17150.0f / sp;
  }
}

// ---------------- fused, ZERO-BARRIER: each wave owns 2 rows end-to-end ----------------
__global__ __launch_bounds__(512) void fused_kernel(
    const float* __restrict__ phase, const float* __restrict__ comb,
    const _Float16* __restrict__ basisT,
    const float* __restrict__ scalar, const float* __restrict__ obs_m,
    const float* __restrict__ rel_m, const float* __restrict__ stpacc,
    float* __restrict__ out0, float* __restrict__ out1) {
  __shared__ _Float16 uLDS[ROWS * KROW];     // 34048 B (wave w: rows 2w,2w+1)
  __shared__ float cumS[8][2][4][64];        // 16384 B (wave-private cum slices)

  const int lane = threadIdx.x & 63;
  const int w = __builtin_amdgcn_readfirstlane(threadIdx.x >> 6);  // 0..7
  const int row0 = blockIdx.x * ROWS;

  // ---- Phase 1 (wave-local): trough for row 2w+k2 -> own LDS slice; returns rowScale ----
  auto trough = [&](int k2) -> float {
    const int rl = 2 * w + k2;
    const int row = row0 + rl;
    const int b = row >> 11;
    const int t = row & 2047;
    const float* prow  = phase + (size_t)row * Fn;
    const float* c0row = comb + ((size_t)(b * 2 + 0) * Tn + t) * Fn;
    const float* c1row = comb + ((size_t)(b * 2 + 1) * Tn + t) * Fn;

    float4 pv[5], c0v[5], c1v[5];
#pragma unroll
    for (int it = 0; it < 5; ++it) {
      const int i = lane + 64 * it;
      if (i < 256) {
        pv[it]  = *(const float4*)(prow  + 4 * i);
        c0v[it] = *(const float4*)(c0row + 4 * i);
        c1v[it] = *(const float4*)(c1row + 4 * i);
      } else if (i == 256) {
        pv[it]  = make_float4(prow[1024],  0.f, 0.f, 0.f);
        c0v[it] = make_float4(c0row[1024], 0.f, 0.f, 0.f);
        c1v[it] = make_float4(c1row[1024], 0.f, 0.f, 0.f);
      } else {
        pv[it]  = make_float4(0.f, 0.f, 0.f, 0.f);
        c0v[it] = make_float4(0.f, 0.f, 0.f, 0.f);
        c1v[it] = make_float4(0.f, 0.f, 0.f, 0.f);
      }
    }

    float s = 0.f;
#pragma unroll
    for (int it = 0; it < 5; ++it)
      s += pv[it].x + pv[it].y + pv[it].z + pv[it].w;
    s = waveReduceSum(s);
    const float mean_lm = s * (1.0f / 1025.0f);

    _Float16* urow = uLDS + (size_t)rl * KROW;
    float su = 0.f;
#pragma unroll
    for (int it = 0; it < 5; ++it) {
      const int i = lane + 64 * it;
      float4 u;
      const float* pf = (const float*)&pv[it];
      const float* q0 = (const float*)&c0v[it];
      const float* q1 = (const float*)&c1v[it];
      float* uf = (float*)&u;
#pragma unroll
      for (int c2 = 0; c2 < 4; ++c2) {
        float tr = fmaxf(mean_lm - pf[c2], 0.f);
        float d1 = fabsf(q1[c2]) + 0.25f * fabsf(q0[c2]);
        uf[c2] = tr * (1.f + d1);
      }
      if (i > 256) { u.x = 0.f; u.y = 0.f; u.z = 0.f; u.w = 0.f; }
      else if (i == 256) { u.y = 0.f; u.z = 0.f; u.w = 0.f; }
      su += u.x + u.y + u.z + u.w;
      if (i < 264) {                       // quads 257..263 store zeros (k tail)
        f16x4 hv;
#pragma unroll
        for (int c2 = 0; c2 < 4; ++c2) hv[c2] = (_Float16)uf[c2];
        *(f16x4*)(urow + 4 * i) = hv;
      }
    }
    su = waveReduceSum(su);
    return 1.0f / fmaxf(su * (1.0f / 1025.0f), EPSF);
  };

  const float rs0 = trough(0);
  const float rs1 = trough(1);

  asm volatile("s_waitcnt lgkmcnt(0)" ::: "memory");   // own u-slice visible to own reads
  __builtin_amdgcn_sched_barrier(0);

  // ---- Phase 2 (wave-local MFMA): A rows 0,1 = own rows (rows 2..15 dups, discarded) ----
  const int m16 = lane & 15;
  const int kg = lane >> 4;
  const _Float16* ALp = uLDS + (size_t)(2 * w + (m16 & 1)) * KROW + kg * 8;
  const _Float16* B0 = basisT + (size_t)(m16)      * KP + kg * 8;
  const _Float16* B1 = basisT + (size_t)(16 + m16) * KP + kg * 8;
  const _Float16* B2 = basisT + (size_t)(32 + m16) * KP + kg * 8;
  const _Float16* B3 = basisT + (size_t)(48 + m16) * KP + kg * 8;

  f32x4 acc0 = {0.f, 0.f, 0.f, 0.f};
  f32x4 acc1 = acc0, acc2 = acc0, acc3 = acc0;

  auto loadA = [&](int kt) { return *(const f16x8*)(ALp + kt * 32); };
  auto tile = [&](int kt, f16x8 a) {
    acc0 = __builtin_amdgcn_mfma_f32_16x16x32_f16(a, *(const f16x8*)(B0 + kt * 32), acc0, 0, 0, 0);
    acc1 = __builtin_amdgcn_mfma_f32_16x16x32_f16(a, *(const f16x8*)(B1 + kt * 32), acc1, 0, 0, 0);
    acc2 = __builtin_amdgcn_mfma_f32_16x16x32_f16(a, *(const f16x8*)(B2 + kt * 32), acc2, 0, 0, 0);
    acc3 = __builtin_amdgcn_mfma_f32_16x16x32_f16(a, *(const f16x8*)(B3 + kt * 32), acc3, 0, 0, 0);
  };
  // spill cumulative snapshot to wave-private cum slice (C rows 0,1 live in lanes 0..15)
  auto spill = [&](int slot) {
    if (lane < 16) {
      cumS[w][0][slot][lane]      = acc0[0];
      cumS[w][0][slot][16 + lane] = acc1[0];
      cumS[w][0][slot][32 + lane] = acc2[0];
      cumS[w][0][slot][48 + lane] = acc3[0];
      cumS[w][1][slot][lane]      = acc0[1];
      cumS[w][1][slot][16 + lane] = acc1[1];
      cumS[w][1][slot][32 + lane] = acc2[1];
      cumS[w][1][slot][48 + lane] = acc3[1];
    }
  };
  auto boundary = [&](int kt, int KB, int slot) {
    f16x8 a = loadA(kt);
    const int kb = kt * 32 + kg * 8;
    f16x8 alo, ahi;
#pragma unroll
    for (int j = 0; j < 8; ++j) {
      bool lo = (kb + j) < KB;
      alo[j] = lo ? a[j] : (_Float16)0.f;
      ahi[j] = lo ? (_Float16)0.f : a[j];
    }
    tile(kt, alo);
    spill(slot);
    tile(kt, ahi);
  };

  boundary(0, 22, 0);                      // cum to k=22
  tile(1, loadA(1));
  boundary(2, 86, 1);                      // cum to k=86
#pragma unroll
  for (int kt = 3; kt < 10; ++kt) tile(kt, loadA(kt));
  boundary(10, 342, 2);                    // cum to k=342
#pragma unroll
  for (int kt = 11; kt < 33; ++kt) tile(kt, loadA(kt));
  spill(3);                                // total (k=1025)

  asm volatile("s_waitcnt lgkmcnt(0)" ::: "memory");   // cum writes visible to own reads
  __builtin_amdgcn_sched_barrier(0);

  // ---- Phase 3 (wave-local epilogue): rows 2w, 2w+1; lane = d ----
  auto EPI = [&](int k2, float rs) {
    const int rl = 2 * w + k2;
    const size_t bt = (size_t)(row0 + rl);

    float sv = fmaxf(stpacc[bt * Dn + lane], 0.f);

    float s22   = cumS[w][k2][0][lane];
    float s86   = cumS[w][k2][1][lane];
    float s342  = cumS[w][k2][2][lane];
    float total = cumS[w][k2][3][lane];

    float ssum = waveReduceSum(sv);
    float stp = sv / fmaxf(ssum * (1.0f / 64.0f), EPSF);

    float4 scv = *(const float4*)(scalar + bt * 4);
    float4 om  = *(const float4*)(obs_m  + bt * 4);
    float4 rm  = *(const float4*)(rel_m  + bt * 4);
    float obs_q = (om.x + om.y + om.z + om.w) * 0.25f;
    float rel_q = (rm.x + rm.y + rm.z + rm.w) * 0.25f;
    float is_snd = fminf(fmaxf(scv.x, 0.f), 1.f);
    float rho = fabsf(fminf(fmaxf(scv.y, -1.f), 1.f));

    float c0 = total * rs * (1.0f / 1025.0f);
    float c1 = s22 * rs * (1.0f / 22.0f);
    float c2 = (s86 - s22) * rs * (1.0f / 64.0f);
    float c3 = (s342 - s86) * rs * (1.0f / 256.0f);
    float c4 = (total - s342) * rs * (1.0f / 683.0f);

    float mean10 = (c0 + c1 + c2 + c3 + c4 + stp + obs_q + rel_q + is_snd + rho) * 0.1f;
    float logit = mean10 * (0.5f + 0.5f * is_snd);

    float2* op = (float2*)(out0 + (bt * Dn + lane) * 10);
    op[0] = make_float2(c0, c1);
    op[1] = make_float2(c2, c3);
    op[2] = make_float2(c4, stp);
    op[3] = make_float2(obs_q, rel_q);
    op[4] = make_float2(is_snd, rho);
    out1[bt * Dn + lane] = logit;
  };
  EPI(0, rs0);
  EPI(1, rs1);
}

extern "C" void kernel_launch(void* const* d_in, const int* in_sizes, int n_in,
                              void* d_out, int out_size, void* d_ws, size_t ws_size,
                              hipStream_t stream) {
  const float* phase   = (const float*)d_in[0];
  const float* comb    = (const float*)d_in[1];
  const float* scalar  = (const float*)d_in[2];
  const float* obs_m   = (const float*)d_in[3];
  const float* rel_m   = (const float*)d_in[4];
  const float* stpacc  = (const float*)d_in[5];
  const float* freq    = (const float*)d_in[6];
  const float* spacing = (const float*)d_in[7];

  float* out  = (float*)d_out;
  float* out0 = out;                                    // (B,T,D,10)
  float* out1 = out + (size_t)Bn * Tn * Dn * 10;        // (B,T,D)
  float* out2 = out1 + (size_t)Bn * Tn * Dn;            // (D,)
  float* out3 = out2 + Dn;                              // (D,)

  _Float16* basisT = (_Float16*)d_ws;                   // 64*KP fp16 = 135 KB

  prep_kernel<<<Dn, 256, 0, stream>>>(freq, spacing, basisT, out2, out3);
  fused_kernel<<<Bn * Tn / ROWS, 512, 0, stream>>>(
      phase, comb, basisT, scalar, obs_m, rel_m, stpacc, out0, out1);
}

// Round 15
// 118.428 us; speedup vs baseline: 1.9338x; 1.9338x over previous
//
#include <hip/hip_runtime.h>
#include <hip/hip_fp16.h>
#include <math.h>

#define Bn 16
#define Tn 2048
#define Fn 1025
#define KP 1056       // padded K = 33 * 32 (basisT row stride)
#define KROW 1064     // LDS u row stride in fp16 (2128 B -> 20 mod 32 banks, 2-way = free)
#define ROWS 16       // rows per block; 8 waves -> 2 rows/wave
#define NSLOT 7       // q0..q3, s22, s86, s342partial
#define Dn 64
#define EPSF 1e-6f

typedef __attribute__((ext_vector_type(8))) _Float16 f16x8;
typedef __attribute__((ext_vector_type(4))) _Float16 f16x4;
typedef __attribute__((ext_vector_type(4))) float f32x4;

__device__ inline float waveReduceSum(float v) {
#pragma unroll
  for (int off = 32; off > 0; off >>= 1) v += __shfl_xor(v, off, 64);
  return v;
}

// ---------------- prep: basisT[d][k] fp16 (normalized), spacing outputs ----------------
__global__ __launch_bounds__(256) void prep_kernel(
    const float* __restrict__ freq, const float* __restrict__ spacing,
    _Float16* __restrict__ basisT, float* __restrict__ out2, float* __restrict__ out3) {
  __shared__ float wsum[4];
  const int d = blockIdx.x;
  const int tid = threadIdx.x;
  const float sp = fmaxf(spacing[d], 1e-6f);

  float pv[5];
  float lsum = 0.f;
#pragma unroll
  for (int it = 0; it < 5; ++it) {
    int f = tid + 256 * it;
    float p = 0.f;
    if (f < Fn) {
      double arg = 6.2831853071795864769 * (double)(freq[f] / sp);
      p = 0.5f * (1.0f + (float)cos(arg));
      lsum += p;
    }
    pv[it] = p;
  }
  float s = waveReduceSum(lsum);
  if ((tid & 63) == 0) wsum[tid >> 6] = s;
  __syncthreads();
  float inv = 1.0f / fmaxf((wsum[0] + wsum[1] + wsum[2] + wsum[3]) * (1.0f / 1025.0f), EPSF);

#pragma unroll
  for (int it = 0; it < 5; ++it) {
    int f = tid + 256 * it;
    if (f < KP) basisT[(size_t)d * KP + f] = (_Float16)(pv[it] * inv);
  }
  if (tid == 0) {
    out2[d] = spacing[d];
    out3[d] = 17150.0f / sp;
  }
}

// ---------------- fused: 8 waves, 2 rows/wave, k-quarter MFMA ----------------
__global__ __launch_bounds__(512) void fused_kernel(
    const float* __restrict__ phase, const float* __restrict__ comb,
    const _Float16* __restrict__ basisT,
    const float* __restrict__ scalar, const float* __restrict__ obs_m,
    const float* __restrict__ rel_m, const float* __restrict__ stpacc,
    float* __restrict__ out0, float* __restrict__ out1) {
  __shared__ _Float16 uLDS[ROWS * KROW];            // 34048 B
  __shared__ float cumS[ROWS * NSLOT * 65];         // 29120 B
  __shared__ float rowScale[ROWS];

  const int lane = threadIdx.x & 63;
  const int w = __builtin_amdgcn_readfirstlane(threadIdx.x >> 6);  // 0..7
  const int row0 = blockIdx.x * ROWS;

  // ---- Phase 1: wave w -> rows 2w, 2w+1 (chain length 2) ----
#pragma unroll 1
  for (int k2 = 0; k2 < 2; ++k2) {
    const int rl = 2 * w + k2;
    const int row = row0 + rl;
    const int b = row >> 11;
    const int t = row & 2047;
    const float* prow  = phase + (size_t)row * Fn;
    const float* c0row = comb + ((size_t)(b * 2 + 0) * Tn + t) * Fn;
    const float* c1row = comb + ((size_t)(b * 2 + 1) * Tn + t) * Fn;

    float4 pv[5], c0v[5], c1v[5];
#pragma unroll
    for (int it = 0; it < 5; ++it) {
      const int i = lane + 64 * it;
      if (i < 256) {
        pv[it]  = *(const float4*)(prow  + 4 * i);
        c0v[it] = *(const float4*)(c0row + 4 * i);
        c1v[it] = *(const float4*)(c1row + 4 * i);
      } else if (i == 256) {
        pv[it]  = make_float4(prow[1024],  0.f, 0.f, 0.f);
        c0v[it] = make_float4(c0row[1024], 0.f, 0.f, 0.f);
        c1v[it] = make_float4(c1row[1024], 0.f, 0.f, 0.f);
      } else {
        pv[it]  = make_float4(0.f, 0.f, 0.f, 0.f);
        c0v[it] = make_float4(0.f, 0.f, 0.f, 0.f);
        c1v[it] = make_float4(0.f, 0.f, 0.f, 0.f);
      }
    }

    float s = 0.f;
#pragma unroll
    for (int it = 0; it < 5; ++it)
      s += pv[it].x + pv[it].y + pv[it].z + pv[it].w;
    s = waveReduceSum(s);
    const float mean_lm = s * (1.0f / 1025.0f);

    _Float16* urow = uLDS + (size_t)rl * KROW;
    float su = 0.f;
#pragma unroll
    for (int it = 0; it < 5; ++it) {
      const int i = lane + 64 * it;
      float4 u;
      const float* pf = (const float*)&pv[it];
      const float* q0 = (const float*)&c0v[it];
      const float* q1 = (const float*)&c1v[it];
      float* uf = (float*)&u;
#pragma unroll
      for (int c2 = 0; c2 < 4; ++c2) {
        float tr = fmaxf(mean_lm - pf[c2], 0.f);
        float d1 = fabsf(q1[c2]) + 0.25f * fabsf(q0[c2]);
        uf[c2] = tr * (1.f + d1);
      }
      if (i > 256) { u.x = 0.f; u.y = 0.f; u.z = 0.f; u.w = 0.f; }
      else if (i == 256) { u.y = 0.f; u.z = 0.f; u.w = 0.f; }
      su += u.x + u.y + u.z + u.w;
      if (i < 264) {                       // quads 257..263 store zeros (k tail)
        f16x4 hv;
#pragma unroll
        for (int c2 = 0; c2 < 4; ++c2) hv[c2] = (_Float16)uf[c2];
        *(f16x4*)(urow + 4 * i) = hv;
      }
    }
    su = waveReduceSum(su);
    if (lane == 0) rowScale[rl] = 1.0f / fmaxf(su * (1.0f / 1025.0f), EPSF);
  }
  __syncthreads();

  // ---- Phase 2: MFMA. wave = (kq = w>>1 in 0..3, nh = w&1); 16 real rows ----
  const int m16 = lane & 15;
  const int kg = lane >> 4;
  const int nh = w & 1;
  const int kq = w >> 1;
  const int d0 = nh * 32 + m16;

  const _Float16* ALp = uLDS + (size_t)m16 * KROW + kg * 8;
  const _Float16* B0 = basisT + (size_t)d0 * KP + kg * 8;
  const _Float16* B1 = basisT + (size_t)(d0 + 16) * KP + kg * 8;

  f32x4 acc0 = {0.f, 0.f, 0.f, 0.f};
  f32x4 acc1 = {0.f, 0.f, 0.f, 0.f};

  auto loadA = [&](int kt) { return *(const f16x8*)(ALp + kt * 32); };
  auto tileA = [&](int kt, f16x8 a) {
    f16x8 b0 = *(const f16x8*)(B0 + kt * 32);
    f16x8 b1 = *(const f16x8*)(B1 + kt * 32);
    acc0 = __builtin_amdgcn_mfma_f32_16x16x32_f16(a, b0, acc0, 0, 0, 0);
    acc1 = __builtin_amdgcn_mfma_f32_16x16x32_f16(a, b1, acc1, 0, 0, 0);
  };
  auto stor = [&](int slot, const f32x4& v0, const f32x4& v1) {
#pragma unroll
    for (int r = 0; r < 4; ++r) {
      const int rr = kg * 4 + r;
      cumS[(rr * NSLOT + slot) * 65 + d0]      = v0[r];
      cumS[(rr * NSLOT + slot) * 65 + d0 + 16] = v1[r];
    }
  };
  auto boundary = [&](int kt, int KB, f32x4& sa, f32x4& sb) {
    f16x8 a = loadA(kt);
    const int kb = kt * 32 + kg * 8;
    f16x8 alo, ahi;
#pragma unroll
    for (int j = 0; j < 8; ++j) {
      bool lo = (kb + j) < KB;
      alo[j] = lo ? a[j] : (_Float16)0.f;
      ahi[j] = lo ? (_Float16)0.f : a[j];
    }
    tileA(kt, alo);
    sa = acc0; sb = acc1;
    tileA(kt, ahi);
  };

  if (kq == 0) {
    f32x4 za = {0.f, 0.f, 0.f, 0.f};
    f32x4 s22a = za, s22b = za, s86a = za, s86b = za;
    boundary(0, 22, s22a, s22b);             // band0 boundary k=22 (kt0)
    tileA(1, loadA(1));
    boundary(2, 86, s86a, s86b);             // band1 boundary k=86 (kt2)
#pragma unroll
    for (int kt = 3; kt < 8; ++kt) tileA(kt, loadA(kt));
    stor(0, acc0, acc1);                     // q0 = kt0..7
    stor(4, s22a, s22b);                     // cum to k=22
    stor(5, s86a, s86b);                     // cum to k=86
  } else if (kq == 1) {
    f32x4 za = {0.f, 0.f, 0.f, 0.f};
    f32x4 s342a = za, s342b = za;
    tileA(8, loadA(8));
    tileA(9, loadA(9));
    boundary(10, 342, s342a, s342b);         // band2 boundary k=342 (kt10)
#pragma unroll
    for (int kt = 11; kt < 17; ++kt) tileA(kt, loadA(kt));
    stor(1, acc0, acc1);                     // q1 = kt8..16
    stor(6, s342a, s342b);                   // kq1 partial to k=342
  } else if (kq == 2) {
#pragma unroll
    for (int kt = 17; kt < 25; ++kt) tileA(kt, loadA(kt));
    stor(2, acc0, acc1);                     // q2 = kt17..24
  } else {
#pragma unroll
    for (int kt = 25; kt < 33; ++kt) tileA(kt, loadA(kt));
    stor(3, acc0, acc1);                     // q3 = kt25..32
  }
  __syncthreads();

  // ---- Phase 3: epilogue. wave w -> rows 2w, 2w+1; lane = d ----
#pragma unroll
  for (int k2 = 0; k2 < 2; ++k2) {
    const int rl = 2 * w + k2;
    const size_t bt = (size_t)(row0 + rl);
    const float rs = rowScale[rl];

    float sv = fmaxf(stpacc[bt * Dn + lane], 0.f);   // issue early

    float q[NSLOT];
#pragma unroll
    for (int s2 = 0; s2 < NSLOT; ++s2)
      q[s2] = cumS[(rl * NSLOT + s2) * 65 + lane];

    float total = q[0] + q[1] + q[2] + q[3];
    float cum342 = q[0] + q[6];

    float ssum = waveReduceSum(sv);
    float stp = sv / fmaxf(ssum * (1.0f / 64.0f), EPSF);

    float4 scv = *(const float4*)(scalar + bt * 4);
    float4 om  = *(const float4*)(obs_m  + bt * 4);
    float4 rm  = *(const float4*)(rel_m  + bt * 4);
    float obs_q = (om.x + om.y + om.z + om.w) * 0.25f;
    float rel_q = (rm.x + rm.y + rm.z + rm.w) * 0.25f;
    float is_snd = fminf(fmaxf(scv.x, 0.f), 1.f);
    float rho = fabsf(fminf(fmaxf(scv.y, -1.f), 1.f));

    float c0 = total * rs * (1.0f / 1025.0f);
    float c1 = q[4] * rs * (1.0f / 22.0f);
    float c2 = (q[5] - q[4]) * rs * (1.0f / 64.0f);
    float c3 = (cum342 - q[5]) * rs * (1.0f / 256.0f);
    float c4 = (total - cum342) * rs * (1.0f / 683.0f);

    float mean10 = (c0 + c1 + c2 + c3 + c4 + stp + obs_q + rel_q + is_snd + rho) * 0.1f;
    float logit = mean10 * (0.5f + 0.5f * is_snd);

    float2* op = (float2*)(out0 + (bt * Dn + lane) * 10);
    op[0] = make_float2(c0, c1);
    op[1] = make_float2(c2, c3);
    op[2] = make_float2(c4, stp);
    op[3] = make_float2(obs_q, rel_q);
    op[4] = make_float2(is_snd, rho);
    out1[bt * Dn + lane] = logit;
  }
}

extern "C" void kernel_launch(void* const* d_in, const int* in_sizes, int n_in,
                              void* d_out, int out_size, void* d_ws, size_t ws_size,
                              hipStream_t stream) {
  const float* phase   = (const float*)d_in[0];
  const float* comb    = (const float*)d_in[1];
  const float* scalar  = (const float*)d_in[2];
  const float* obs_m   = (const float*)d_in[3];
  const float* rel_m   = (const float*)d_in[4];
  const float* stpacc  = (const float*)d_in[5];
  const float* freq    = (const float*)d_in[6];
  const float* spacing = (const float*)d_in[7];

  float* out  = (float*)d_out;
  float* out0 = out;                                    // (B,T,D,10)
  float* out1 = out + (size_t)Bn * Tn * Dn * 10;        // (B,T,D)
  float* out2 = out1 + (size_t)Bn * Tn * Dn;            // (D,)
  float* out3 = out2 + Dn;                              // (D,)

  _Float16* basisT = (_Float16*)d_ws;                   // 64*KP fp16 = 135 KB

  prep_kernel<<<Dn, 256, 0, stream>>>(freq, spacing, basisT, out2, out3);
  fused_kernel<<<Bn * Tn / ROWS, 512, 0, stream>>>(
      phase, comb, basisT, scalar, obs_m, rel_m, stpacc, out0, out1);
}